// Round 29
// baseline (94.978 us; speedup 1.0000x reference)
//
#include <hip/hip_runtime.h>
#include <hip/hip_bf16.h>

// Quantized 3x3 conv via int8 implicit GEMM — persistent 2-tile blocks:
// tile1's prologue loads are issued BEFORE tile0's epilogue stores, so the
// ~3-5us prologue latency hides under the store burst (the one overlap
// mechanism not yet built; R25 ablation: epilogue 24us vs 14.5 floor).
// 448 blocks x 2 tiles (2 output rows each). All else = R28 (proven):
// wave-private 2-slot B ring, counted per-wave vmcnt, setprio MFMA, XCD
// swizzle, transposed-D coalesced epilogue.
// B=32, Cin=128, Cout=256, H=W=56, pad=1. M=(b,h,w64), N=256, K=9x128.
//
// (x-xz)(w-wz) = xi*wi + (128-wz)*xi,  xi=x-128 (int8), wi=w-128 (int8);
// acc = i8gemm + (128-wz)*S,  S = window-sum of xi (pads contribute 0).
//
// xpi8 blob per (b,hh), 8KB: byte(w,c) = w*128 + (c ^ ((w&7)<<4)).
// wt layout: per (s=r*2+ch, wn) a 4KB panel of 64 rows x 64B:
//   byte(nn, kl) = nn*64 + (kl ^ ((nn&3)<<4)),  n = wn*64+nn, cin = ch*64+kl.
// Involution swizzles; staged linearly via global_load_lds, read with the
// same XOR (rule #21).

typedef __attribute__((ext_vector_type(4))) int   i32x4;
typedef __attribute__((ext_vector_type(4))) float f32x4;

#define WTI8_BYTES (18 * 16384)            // 294,912
#define XPI8_BYTES (32 * 58 * 8192)        // 15,204,352

__device__ __forceinline__ void gload_lds16(const void* g, void* l) {
    __builtin_amdgcn_global_load_lds(
        (const __attribute__((address_space(1))) void*)g,
        (__attribute__((address_space(3))) void*)l, 16, 0, 0);
}

// ---- fused prep: blocks <1856 do x-repack+colsum; rest do weight prep ----
__global__ void prep_kernel(const float* __restrict__ x, const float* __restrict__ xzp,
                            const float* __restrict__ w,
                            char* __restrict__ xpi8, int* __restrict__ colsum,
                            char* __restrict__ wt) {
    int tid = threadIdx.x;
    if (blockIdx.x >= 32 * 58) {
        int cidx = (blockIdx.x - 32 * 58) * 256 + tid;   // < 18432
        int byte0 = cidx * 16;
        int s    = byte0 >> 14;
        int wn   = (byte0 >> 12) & 3;
        int e4   = byte0 & 4095;
        int nn   = e4 >> 6;
        int koff = e4 & 63;
        int kl   = koff ^ ((nn & 3) << 4);
        int n = wn * 64 + nn;
        int r = s >> 1, ch = s & 1;
        union { char c[16]; i32x4 v; } u;
#pragma unroll
        for (int j = 0; j < 16; ++j) {
            int cin = ch * 64 + kl + j;
            u.c[j] = (char)((int)w[(size_t)n * 1152 + cin * 9 + r] - 128);
        }
        *(i32x4*)(wt + byte0) = u.v;
        return;
    }
    int bhh = blockIdx.x;
    int b = bhh / 58, hh = bhh % 58;
    char* blob = xpi8 + (size_t)bhh * 8192;
    int wcol = tid & 63;
    int cq = tid >> 6;
    __shared__ int ps[4][64];
    if (hh == 0 || hh == 57) {
        i32x4 z = {0, 0, 0, 0};
        *(i32x4*)(blob + tid * 32)      = z;
        *(i32x4*)(blob + tid * 32 + 16) = z;
        if (cq == 0) colsum[bhh * 64 + wcol] = 0;
        return;
    }
    const int ZX = (int)rintf(*xzp);
    bool valid = (wcol >= 1 && wcol <= 56);
    const float* xb = x + (size_t)b * 128 * 3136 + (size_t)(hh - 1) * 56 +
                      (valid ? (wcol - 1) : 0);
    int csum = 0;
#pragma unroll
    for (int u = 0; u < 2; ++u) {
        union { char c[16]; i32x4 v; } uu;
#pragma unroll
        for (int j = 0; j < 16; ++j) {
            int c = cq * 32 + u * 16 + j;
            int val = valid ? ((int)xb[(size_t)c * 3136] - ZX) : 0;
            uu.c[j] = (char)val;
            csum += val;
        }
        *(i32x4*)(blob + wcol * 128 + ((cq * 32 + u * 16) ^ ((wcol & 7) << 4))) = uu.v;
    }
    ps[cq][wcol] = csum;
    __syncthreads();
    if (cq == 0)
        colsum[bhh * 64 + wcol] = ps[0][wcol] + ps[1][wcol] + ps[2][wcol] + ps[3][wcol];
}

// ---- shared pieces ----
__device__ __forceinline__ void kloop(const char* As, char* bpriv,
                                      const char* bwsrc, int lane,
                                      int l15, int lg, int bfoff,
                                      i32x4 acc[4][8]) {
#pragma unroll
    for (int s = 0; s < 18; ++s) {                 // 9 taps x 2 cin-halves
        const int kh = (s >> 1) / 3, kw = (s >> 1) % 3, ch = s & 1;
        const char* bslot = bpriv + (s & 1) * 4096;
        i32x4 bfr[4];
#pragma unroll
        for (int fn = 0; fn < 4; ++fn)
            bfr[fn] = *(const i32x4*)(bslot + (fn * 16 + l15) * 64 + bfoff);
        i32x4 afr[8];
#pragma unroll
        for (int fm = 0; fm < 8; ++fm) {
            int rowoff = fm >> 2;
            int wv = (fm & 3) * 16 + l15 + kw;
            int wc = wv > 63 ? 63 : wv;            // clamped lanes: dead outputs
            int ab = (rowoff + kh) * 8192 + wc * 128 +
                     ((ch * 64 + lg * 16) ^ ((wc & 7) << 4));
            afr[fm] = *(const i32x4*)(As + ab);
        }
        if (s < 16) {
            asm volatile("s_waitcnt lgkmcnt(0)" ::: "memory");
#pragma unroll
            for (int i = 0; i < 4; ++i)
                gload_lds16(bwsrc + (size_t)(s + 2) * 16384 + i * 1024,
                            bpriv + (s & 1) * 4096 + i * 1024 + lane * 16);
            asm volatile("s_waitcnt vmcnt(4)" ::: "memory");
        } else if (s == 16) {
            asm volatile("s_waitcnt vmcnt(0)" ::: "memory");
        }
        __builtin_amdgcn_s_setprio(1);
#pragma unroll
        for (int fn = 0; fn < 4; ++fn)
#pragma unroll
            for (int fm = 0; fm < 8; ++fm)
                acc[fn][fm] = __builtin_amdgcn_mfma_i32_16x16x64_i8(
                    bfr[fn], afr[fm], acc[fn][fm], 0, 0, 0);
        __builtin_amdgcn_s_setprio(0);
    }
}

__device__ __forceinline__ void epilogue(const i32x4 acc[4][8], const int s2t[2][64],
                                         const float* bias, float Mv, float yzv,
                                         float CWf, int wn, int l15, int lg,
                                         int b, int h0, float* out) {
#pragma unroll
    for (int fn = 0; fn < 4; ++fn) {
#pragma unroll
        for (int reg = 0; reg < 4; ++reg) {
            const int cout = wn * 64 + fn * 16 + lg * 4 + reg;
            const float bv = bias[cout];
#pragma unroll
            for (int fm = 0; fm < 8; ++fm) {
                const int row = fm >> 2;
                const int m = (fm & 3) * 16 + l15;
                if (m < 56) {
                    const size_t rowb =
                        ((size_t)(b * 256 + cout) * 56 + h0 + row) * 56;
                    float af = (float)acc[fn][fm][reg] + CWf * (float)s2t[row][m];
                    float v = (af + bv) * Mv + yzv;
                    v = fmaxf(v, yzv);
                    out[rowb + m] = rintf(v);
                }
            }
        }
    }
}

// ---- main conv: persistent 2-tile blocks ----
__global__ __launch_bounds__(256, 2)
void conv_kernel(const char* __restrict__ wt,
                 const char* __restrict__ xpi8,
                 const int* __restrict__ colsum,
                 const float* __restrict__ bias,
                 const float* __restrict__ Mp,
                 const float* __restrict__ wzp,
                 const float* __restrict__ yzp,
                 float* __restrict__ out) {
    __shared__ __align__(1024) char As[32768];     // A: 4 row-blobs (per tile)
    __shared__ __align__(1024) char Bp[32768];     // 4 waves x 2 slots x 4KB
    __shared__ int s2row[2][2][64];                // [tile][row][m]

    const int tid = threadIdx.x;
    const int lane = tid & 63;
    const int wn = tid >> 6;
    const int l15 = lane & 15, lg = lane >> 4;
    // XCD-bijective swizzle (448 % 8 == 0)
    const int bx = (blockIdx.x % 8) * 56 + (blockIdx.x / 8);
    const int b = bx / 14;
    const int h0 = (bx % 14) * 4;                  // 4 rows = 2 tiles x 2 rows

    char* bpriv = Bp + wn * 8192;
    const char* bwsrc = wt + wn * 4096 + lane * 16;
    const int bfoff = (lg * 16) ^ ((l15 & 3) << 4);

    const float Mv  = *Mp;
    const float yzv = *yzp;
    const float CWf = 128.0f - *wzp;

    // ---- prologue tile0 ----
    const char* ag0 = xpi8 + (size_t)(b * 58 + h0) * 8192;
#pragma unroll
    for (int i = 0; i < 8; ++i)
        gload_lds16(ag0 + i * 4096 + tid * 16, As + i * 4096 + tid * 16);
#pragma unroll
    for (int st = 0; st < 2; ++st)
#pragma unroll
        for (int i = 0; i < 4; ++i)
            gload_lds16(bwsrc + (size_t)st * 16384 + i * 1024,
                        bpriv + st * 4096 + i * 1024 + lane * 16);
    if (tid < 128) {
        int row = tid >> 6, m = tid & 63;
        int s = 0;
        if (m < 56) {
#pragma unroll
            for (int kh = 0; kh < 3; ++kh)
#pragma unroll
                for (int kw = 0; kw < 3; ++kw)
                    s += colsum[(b * 58 + h0 + row + kh) * 64 + m + kw];
        }
        s2row[0][row][m] = s;
    }

    i32x4 acc[4][8];
#pragma unroll
    for (int i = 0; i < 4; ++i)
#pragma unroll
        for (int j = 0; j < 8; ++j)
            acc[i][j] = (i32x4){0, 0, 0, 0};

    __syncthreads();                               // tile0 A/B0/B1 + s2row0

    kloop(As, bpriv, bwsrc, lane, l15, lg, bfoff, acc);

    __syncthreads();                               // all waves done with LDS t0

    // ---- issue tile1 prologue UNDER tile0's epilogue ----
    const char* ag1 = xpi8 + (size_t)(b * 58 + h0 + 2) * 8192;
#pragma unroll
    for (int i = 0; i < 8; ++i)
        gload_lds16(ag1 + i * 4096 + tid * 16, As + i * 4096 + tid * 16);
#pragma unroll
    for (int st = 0; st < 2; ++st)
#pragma unroll
        for (int i = 0; i < 4; ++i)
            gload_lds16(bwsrc + (size_t)st * 16384 + i * 1024,
                        bpriv + st * 4096 + i * 1024 + lane * 16);
    if (tid < 128) {
        int row = tid >> 6, m = tid & 63;
        int s = 0;
        if (m < 56) {
#pragma unroll
            for (int kh = 0; kh < 3; ++kh)
#pragma unroll
                for (int kw = 0; kw < 3; ++kw)
                    s += colsum[(b * 58 + h0 + 2 + row + kh) * 64 + m + kw];
        }
        s2row[1][row][m] = s;
    }

    epilogue(acc, s2row[0], bias, Mv, yzv, CWf, wn, l15, lg, b, h0, out);

    __syncthreads();                               // drains vmcnt: t1 A/B landed

#pragma unroll
    for (int i = 0; i < 4; ++i)
#pragma unroll
        for (int j = 0; j < 8; ++j)
            acc[i][j] = (i32x4){0, 0, 0, 0};

    kloop(As, bpriv, bwsrc, lane, l15, lg, bfoff, acc);

    epilogue(acc, s2row[1], bias, Mv, yzv, CWf, wn, l15, lg, b, h0 + 2, out);
}

extern "C" void kernel_launch(void* const* d_in, const int* in_sizes, int n_in,
                              void* d_out, int out_size, void* d_ws, size_t ws_size,
                              hipStream_t stream) {
    const float* x    = (const float*)d_in[0];
    const float* w    = (const float*)d_in[1];
    const float* bias = (const float*)d_in[2];
    const float* Mp   = (const float*)d_in[3];
    const float* xzp  = (const float*)d_in[4];
    const float* wzp  = (const float*)d_in[5];
    const float* yzp  = (const float*)d_in[6];
    float* out = (float*)d_out;

    char* wt     = (char*)d_ws;                          // 288 KB
    char* xpi8   = wt + WTI8_BYTES;                      // 15.2 MB
    int*  colsum = (int*)(xpi8 + XPI8_BYTES);            // 475 KB

    prep_kernel<<<32 * 58 + 72, 256, 0, stream>>>(x, xzp, w, xpi8, colsum, wt);
    conv_kernel<<<32 * 14, 256, 0, stream>>>(wt, xpi8, colsum, bias, Mp, wzp, yzp, out);
}

// Round 30
// 69.490 us; speedup vs baseline: 1.3668x; 1.3668x over previous
//
#include <hip/hip_runtime.h>
#include <hip/hip_bf16.h>

// Quantized 3x3 conv via int8 implicit GEMM — FINAL/BEST (R28, 69.3us):
// wave-private 2-slot B ring, counted per-wave vmcnt, zero in-loop
// barriers, T5 setprio around MFMA, T1 XCD-bijective swizzle, direct
// transposed-D coalesced epilogue, fused single prep launch.
// B=32, Cin=128, Cout=256, H=W=56, pad=1. M=(b,h,w64), N=256, K=9x128.
//
// (x-xz)(w-wz) = xi*wi + (128-wz)*xi,  xi=x-128 (int8), wi=w-128 (int8);
// acc = i8gemm + (128-wz)*S,  S = window-sum of xi (pads contribute 0).
// All arithmetic integer-exact -> absmax 0.
//
// xpi8 blob per (b,hh), 8KB: byte(w,c) = w*128 + (c ^ ((w&7)<<4)).
// wt layout: per (s=r*2+ch, wn) a 4KB panel of 64 rows x 64B:
//   byte(nn, kl) = nn*64 + (kl ^ ((nn&3)<<4)),  n = wn*64+nn, cin = ch*64+kl.
// Involution swizzles; staged linearly via global_load_lds, read with the
// same XOR (rule #21).
//
// Measured decomposition (R24/R25 REP-ablation): MFMA-only loop 20us @
// MfmaUtil 78%; prep 12us (~traffic floor); epilogue ~24us vs 14.5us
// HBM-write floor (survived repack/overlap attacks); 14 K-loop variants
// within +-3us. Session: 239 -> 69.3us.

typedef __attribute__((ext_vector_type(4))) int   i32x4;
typedef __attribute__((ext_vector_type(4))) float f32x4;

#define WTI8_BYTES (18 * 16384)            // 294,912
#define XPI8_BYTES (32 * 58 * 8192)        // 15,204,352

__device__ __forceinline__ void gload_lds16(const void* g, void* l) {
    __builtin_amdgcn_global_load_lds(
        (const __attribute__((address_space(1))) void*)g,
        (__attribute__((address_space(3))) void*)l, 16, 0, 0);
}

// ---- fused prep: blocks <1856 do x-repack+colsum; rest do weight prep ----
__global__ void prep_kernel(const float* __restrict__ x, const float* __restrict__ xzp,
                            const float* __restrict__ w,
                            char* __restrict__ xpi8, int* __restrict__ colsum,
                            char* __restrict__ wt) {
    int tid = threadIdx.x;
    if (blockIdx.x >= 32 * 58) {
        int cidx = (blockIdx.x - 32 * 58) * 256 + tid;   // < 18432
        int byte0 = cidx * 16;
        int s    = byte0 >> 14;
        int wn   = (byte0 >> 12) & 3;
        int e4   = byte0 & 4095;
        int nn   = e4 >> 6;
        int koff = e4 & 63;
        int kl   = koff ^ ((nn & 3) << 4);
        int n = wn * 64 + nn;
        int r = s >> 1, ch = s & 1;
        union { char c[16]; i32x4 v; } u;
#pragma unroll
        for (int j = 0; j < 16; ++j) {
            int cin = ch * 64 + kl + j;
            u.c[j] = (char)((int)w[(size_t)n * 1152 + cin * 9 + r] - 128);
        }
        *(i32x4*)(wt + byte0) = u.v;
        return;
    }
    int bhh = blockIdx.x;
    int b = bhh / 58, hh = bhh % 58;
    char* blob = xpi8 + (size_t)bhh * 8192;
    int wcol = tid & 63;
    int cq = tid >> 6;
    __shared__ int ps[4][64];
    if (hh == 0 || hh == 57) {
        i32x4 z = {0, 0, 0, 0};
        *(i32x4*)(blob + tid * 32)      = z;
        *(i32x4*)(blob + tid * 32 + 16) = z;
        if (cq == 0) colsum[bhh * 64 + wcol] = 0;
        return;
    }
    const int ZX = (int)rintf(*xzp);
    bool valid = (wcol >= 1 && wcol <= 56);
    const float* xb = x + (size_t)b * 128 * 3136 + (size_t)(hh - 1) * 56 +
                      (valid ? (wcol - 1) : 0);
    int csum = 0;
#pragma unroll
    for (int u = 0; u < 2; ++u) {
        union { char c[16]; i32x4 v; } uu;
#pragma unroll
        for (int j = 0; j < 16; ++j) {
            int c = cq * 32 + u * 16 + j;
            int val = valid ? ((int)xb[(size_t)c * 3136] - ZX) : 0;
            uu.c[j] = (char)val;
            csum += val;
        }
        *(i32x4*)(blob + wcol * 128 + ((cq * 32 + u * 16) ^ ((wcol & 7) << 4))) = uu.v;
    }
    ps[cq][wcol] = csum;
    __syncthreads();
    if (cq == 0)
        colsum[bhh * 64 + wcol] = ps[0][wcol] + ps[1][wcol] + ps[2][wcol] + ps[3][wcol];
}

// ---- main conv ----
__global__ __launch_bounds__(256, 2)
void conv_kernel(const char* __restrict__ wt,
                 const char* __restrict__ xpi8,
                 const int* __restrict__ colsum,
                 const float* __restrict__ bias,
                 const float* __restrict__ Mp,
                 const float* __restrict__ wzp,
                 const float* __restrict__ yzp,
                 float* __restrict__ out) {
    __shared__ __align__(1024) char As[32768];     // A: 4 row-blobs, shared
    __shared__ __align__(1024) char Bp[32768];     // 4 waves x 2 slots x 4KB
    __shared__ int s2row[2][64];

    const int tid = threadIdx.x;
    const int lane = tid & 63;
    const int wn = tid >> 6;                       // 0..3: 64-cout slice
    const int l15 = lane & 15, lg = lane >> 4;
    // T1: XCD-bijective swizzle (nwg=896, 896%8==0 -> simple form bijective)
    const int bx = (blockIdx.x % 8) * 112 + (blockIdx.x / 8);
    const int b = bx / 28;
    const int h0 = (bx % 28) * 2;                  // 2 output rows per block

    char* bpriv = Bp + wn * 8192;                  // this wave's 2-slot ring
    const char* bwsrc = wt + wn * 4096 + lane * 16;
    const int bfoff = (lg * 16) ^ ((l15 & 3) << 4);

    // ---- prologue: A (32KB); B stages 0,1 -> slots 0,1; S2 rows ----
    const char* agbase = xpi8 + (size_t)(b * 58 + h0) * 8192;
#pragma unroll
    for (int i = 0; i < 8; ++i)
        gload_lds16(agbase + i * 4096 + tid * 16, As + i * 4096 + tid * 16);
#pragma unroll
    for (int st = 0; st < 2; ++st)
#pragma unroll
        for (int i = 0; i < 4; ++i)
            gload_lds16(bwsrc + (size_t)st * 16384 + i * 1024,
                        bpriv + st * 4096 + i * 1024 + lane * 16);
    if (tid < 128) {
        int row = tid >> 6, m = tid & 63;
        int s = 0;
        if (m < 56) {
#pragma unroll
            for (int kh = 0; kh < 3; ++kh)
#pragma unroll
                for (int kw = 0; kw < 3; ++kw)
                    s += colsum[(b * 58 + h0 + row + kh) * 64 + m + kw];
        }
        s2row[row][m] = s;
    }

    i32x4 acc[4][8];                               // [fn][fm]: row=cout, col=m
#pragma unroll
    for (int i = 0; i < 4; ++i)
#pragma unroll
        for (int j = 0; j < 8; ++j)
            acc[i][j] = (i32x4){0, 0, 0, 0};

    __syncthreads();                               // the ONLY barrier

#pragma unroll
    for (int s = 0; s < 18; ++s) {                 // 9 taps x 2 cin-halves
        const int kh = (s >> 1) / 3, kw = (s >> 1) % 3, ch = s & 1;
        const char* bslot = bpriv + (s & 1) * 4096;
        i32x4 bfr[4];
#pragma unroll
        for (int fn = 0; fn < 4; ++fn)
            bfr[fn] = *(const i32x4*)(bslot + (fn * 16 + l15) * 64 + bfoff);
        i32x4 afr[8];
#pragma unroll
        for (int fm = 0; fm < 8; ++fm) {
            int rowoff = fm >> 2;                  // 0..1: output row
            int wv = (fm & 3) * 16 + l15 + kw;
            int wc = wv > 63 ? 63 : wv;            // clamped lanes: dead outputs
            int ab = (rowoff + kh) * 8192 + wc * 128 +
                     ((ch * 64 + lg * 16) ^ ((wc & 7) << 4));
            afr[fm] = *(const i32x4*)(As + ab);
        }
        if (s < 16) {
            asm volatile("s_waitcnt lgkmcnt(0)" ::: "memory");
#pragma unroll
            for (int i = 0; i < 4; ++i)
                gload_lds16(bwsrc + (size_t)(s + 2) * 16384 + i * 1024,
                            bpriv + (s & 1) * 4096 + i * 1024 + lane * 16);
            asm volatile("s_waitcnt vmcnt(4)" ::: "memory");
        } else if (s == 16) {
            asm volatile("s_waitcnt vmcnt(0)" ::: "memory");
        }
        __builtin_amdgcn_s_setprio(1);             // T5: favor MFMA-entering wave
#pragma unroll
        for (int fn = 0; fn < 4; ++fn)
#pragma unroll
            for (int fm = 0; fm < 8; ++fm)
                acc[fn][fm] = __builtin_amdgcn_mfma_i32_16x16x64_i8(
                    bfr[fn], afr[fm], acc[fn][fm], 0, 0, 0);
        __builtin_amdgcn_s_setprio(0);
    }

    // ---- epilogue: direct transposed-D stores (coalesced in m) ----
    const float Mv  = *Mp;
    const float yzv = *yzp;
    const float CWf = 128.0f - *wzp;               // (128 - w_zero)
#pragma unroll
    for (int fn = 0; fn < 4; ++fn) {
#pragma unroll
        for (int reg = 0; reg < 4; ++reg) {
            const int cout = wn * 64 + fn * 16 + lg * 4 + reg;
            const float bv = bias[cout];
#pragma unroll
            for (int fm = 0; fm < 8; ++fm) {
                const int row = fm >> 2;
                const int m = (fm & 3) * 16 + l15; // lane-contiguous
                if (m < 56) {
                    const size_t rowb =
                        ((size_t)(b * 256 + cout) * 56 + h0 + row) * 56;
                    float af = (float)acc[fn][fm][reg] +
                               CWf * (float)s2row[row][m];
                    float v = (af + bv) * Mv + yzv;
                    v = fmaxf(v, yzv);
                    out[rowb + m] = rintf(v);
                }
            }
        }
    }
}

extern "C" void kernel_launch(void* const* d_in, const int* in_sizes, int n_in,
                              void* d_out, int out_size, void* d_ws, size_t ws_size,
                              hipStream_t stream) {
    const float* x    = (const float*)d_in[0];
    const float* w    = (const float*)d_in[1];
    const float* bias = (const float*)d_in[2];
    const float* Mp   = (const float*)d_in[3];
    const float* xzp  = (const float*)d_in[4];
    const float* wzp  = (const float*)d_in[5];
    const float* yzp  = (const float*)d_in[6];
    float* out = (float*)d_out;

    char* wt     = (char*)d_ws;                          // 288 KB
    char* xpi8   = wt + WTI8_BYTES;                      // 15.2 MB
    int*  colsum = (int*)(xpi8 + XPI8_BYTES);            // 475 KB

    prep_kernel<<<32 * 58 + 72, 256, 0, stream>>>(x, xzp, w, xpi8, colsum, wt);
    conv_kernel<<<32 * 28, 256, 0, stream>>>(wt, xpi8, colsum, bias, Mp, wzp, yzp, out);
}